// Round 12
// baseline (360.336 us; speedup 1.0000x reference)
//
#include <hip/hip_runtime.h>
#include <math.h>

#define B_   2
#define N_   2048
#define DIM_ 512
#define NH_  8
#define HD_  64
#define K_   32
#define PD_  16
#define TOK_ (B_*N_)     // 4096 rows
#define FFN_ 2048
#define QKV_ (3*DIM_)    // 1536
#define KV_  1024        // k|v bf16 row length

typedef __bf16 bf16x8 __attribute__((ext_vector_type(8)));
typedef float  f32x4  __attribute__((ext_vector_type(4)));

__device__ __forceinline__ unsigned short f2bf(float f) {
    unsigned int u = __float_as_uint(f);
    u = (u + 0x7fffu + ((u >> 16) & 1u)) >> 16;
    return (unsigned short)u;
}

__device__ __forceinline__ float bflo(unsigned u) { return __uint_as_float(u << 16); }
__device__ __forceinline__ float bfhi(unsigned u) { return __uint_as_float(u & 0xffff0000u); }

__device__ __forceinline__ float gelu_tanh(float x) {
    float x3 = x * x * x;
    return 0.5f * x * (1.f + tanhf(0.7978845608028654f * (x + 0.044715f * x3)));
}

__device__ __forceinline__ float tanh_fast(float x) {
    float e = __expf(2.f * x);
    return 1.f - 2.f / (e + 1.f);
}

__device__ __forceinline__ int lane_mbcnt(unsigned long long m) {
    return __builtin_amdgcn_mbcnt_hi((unsigned)(m >> 32),
           __builtin_amdgcn_mbcnt_lo((unsigned)m, 0));
}

// async global->LDS, 16B per lane. LDS dst must be wave-uniform base + lane*16.
#define GLOAD_LDS16(g, l) __builtin_amdgcn_global_load_lds(                        \
    (const __attribute__((address_space(1))) unsigned int*)(const void*)(g),       \
    (__attribute__((address_space(3))) unsigned int*)(void*)(l), 16, 0, 0)

// ---------------------------------------------------------------------------
// GEMM: C[M,N] = A[M,Kd] @ Bt[N,Kd]^T, BK=64, 8-chunk XOR swizzle (0 bank
// conflicts, staging lane-ordered for global_load_lds). 256 thr, 4 waves 2x2.
// EPI: 0 +bias->fp32 ; 1 +bias+res->fp32 ; 2 gelu(+bias)->bf16
//      3 QKV split: col<512 -> q fp32; col>=512 -> kv bf16 [row][1024]
// ---------------------------------------------------------------------------
template<int EPI, int BM, int BN>
__global__ __launch_bounds__(256)
void gemm_bf16_kernel(const unsigned short* __restrict__ A,
                      const unsigned short* __restrict__ Bt,
                      const float* __restrict__ bias,
                      const float* __restrict__ res,
                      float* __restrict__ Cf,
                      unsigned short* __restrict__ Cb,
                      int N, int Kd)
{
    constexpr int WM = BM / 2;
    constexpr int WN = BN / 2;
    constexpr int FM = WM / 16;
    constexpr int FN = WN / 16;

    __shared__ __align__(16) unsigned short smem[(BM+BN)*64];
    unsigned short* As_ = smem;            // BM rows x 128B
    unsigned short* Bs_ = smem + BM * 64;  // BN rows x 128B

    int t    = threadIdx.x;
    int lane = t & 63;
    int wid  = t >> 6;
    int wm   = wid >> 1, wn = wid & 1;
    int bm0  = blockIdx.y * BM;
    int bn0  = blockIdx.x * BN;
    int quad = lane >> 4;
    int rlo  = lane & 15;

    f32x4 acc[FM][FN] = {};

    for (int k0 = 0; k0 < Kd; k0 += 64) {
#pragma unroll
        for (int l = 0; l < BM/32; l++) {
            int idx = l*256 + t;
            int r   = idx >> 3;
            int g   = (idx & 7) ^ (r & 7);
            GLOAD_LDS16(A + (size_t)(bm0 + r) * Kd + k0 + g*8, As_ + idx*8);
        }
#pragma unroll
        for (int l = 0; l < BN/32; l++) {
            int idx = l*256 + t;
            int r   = idx >> 3;
            int g   = (idx & 7) ^ (r & 7);
            GLOAD_LDS16(Bt + (size_t)(bn0 + r) * Kd + k0 + g*8, Bs_ + idx*8);
        }
        __syncthreads();

        bf16x8 af[FM][2], bfr[FN][2];
#pragma unroll
        for (int mi = 0; mi < FM; mi++) {
            int r = wm*WM + mi*16 + rlo;
#pragma unroll
            for (int s = 0; s < 2; s++)
                af[mi][s] = *(const bf16x8*)(As_ + r*64 + ((s*4 + quad) ^ (r & 7))*8);
        }
#pragma unroll
        for (int ni = 0; ni < FN; ni++) {
            int r = wn*WN + ni*16 + rlo;
#pragma unroll
            for (int s = 0; s < 2; s++)
                bfr[ni][s] = *(const bf16x8*)(Bs_ + r*64 + ((s*4 + quad) ^ (r & 7))*8);
        }
#pragma unroll
        for (int s = 0; s < 2; s++)
#pragma unroll
            for (int mi = 0; mi < FM; mi++)
#pragma unroll
                for (int ni = 0; ni < FN; ni++)
                    acc[mi][ni] = __builtin_amdgcn_mfma_f32_16x16x32_bf16(
                        af[mi][s], bfr[ni][s], acc[mi][ni], 0, 0, 0);
        __syncthreads();
    }

    // epilogue: D row = quad*4 + r, col = rlo within each 16x16 tile
#pragma unroll
    for (int mi = 0; mi < FM; mi++) {
#pragma unroll
        for (int ni = 0; ni < FN; ni++) {
            int col = bn0 + wn*WN + ni*16 + rlo;
            float bv = bias[col];
#pragma unroll
            for (int r = 0; r < 4; r++) {
                int row = bm0 + wm*WM + mi*16 + quad*4 + r;
                float val = acc[mi][ni][r] + bv;
                if (EPI == 1) val += res[(size_t)row * N + col];
                if (EPI == 2) {
                    val = gelu_tanh(val);
                    Cb[(size_t)row * N + col] = f2bf(val);
                } else if (EPI == 3) {
                    if (col < DIM_) Cf[(size_t)row * DIM_ + col] = val;
                    else            Cb[(size_t)row * KV_ + (col - DIM_)] = f2bf(val);
                } else {
                    Cf[(size_t)row * N + col] = val;
                }
            }
        }
    }
}

// ---------------------------------------------------------------------------
// top-K extraction helper: lt pass (order irrelevant; merge re-ranks) + eq
// pass in ascending-j order (exact jax.lax.top_k lower-index-first).
// j = jbase + (tt>>2)*256 + lane*4 + (tt&3).
// ---------------------------------------------------------------------------
__device__ __forceinline__ void extract_row(const unsigned* rb, unsigned T,
                                            int cnt_lt, int m,
                                            unsigned long long* crow,
                                            int hw, int jbase, int lane)
{
    int ltpos = 0;
#pragma unroll
    for (int tt = 0; tt < 16; tt++) {
        bool is_lt = rb[tt] < T;
        unsigned long long mlt = __ballot(is_lt);
        int p = ltpos + lane_mbcnt(mlt);
        if (is_lt) {
            int j = jbase + (tt >> 2)*256 + lane*4 + (tt & 3);
            crow[hw*K_ + p] = ((unsigned long long)rb[tt] << 32) | (unsigned)j;
        }
        ltpos += __popcll(mlt);
    }
    int eqpos = 0;
#pragma unroll
    for (int jg = 0; jg < 4; jg++) {
        bool iseq[4]; unsigned long long meq[4]; int bel[4];
#pragma unroll
        for (int jj = 0; jj < 4; jj++) {
            iseq[jj] = (rb[jg*4+jj] == T);
            meq[jj]  = __ballot(iseq[jj]);
            bel[jj]  = lane_mbcnt(meq[jj]);
        }
        int lane_prefix = bel[0] + bel[1] + bel[2] + bel[3];
        int within = 0;
#pragma unroll
        for (int jj = 0; jj < 4; jj++) {
            int p = eqpos + lane_prefix + within;
            if (iseq[jj] && p < m) {
                int j = jbase + jg*256 + lane*4 + jj;
                crow[hw*K_ + cnt_lt + p] =
                    ((unsigned long long)rb[jg*4+jj] << 32) | (unsigned)j;
            }
            within += iseq[jj] ? 1 : 0;
        }
        eqpos += __popcll(meq[0]) + __popcll(meq[1]) + __popcll(meq[2]) + __popcll(meq[3]);
    }
}

// ---------------------------------------------------------------------------
// dist + exact top-K body (independent of all weight prep). Block = 4 rows.
// Wave (rg, hw): rows {4id+2rg, 4id+2rg+1} over j-half hw*1024.
// Lane owns 4 consecutive j per group (row reads = 64B/lane, coalesced
// cacheline-wise); nj computed inline; diff = ni + nj - 2<pi,pj> (expansion:
// 12 FMA per d per 4-j vs 16 for sub-square, no sq loads, no posT).
// Interleaved 2-row radix select + exact-rank merge (jax.lax.top_k order).
// ---------------------------------------------------------------------------
__device__ __forceinline__ void dist_topk_body(
    unsigned long long (*cand)[64], int id,
    const float* __restrict__ pos, float cc,
    int* __restrict__ topk_idx, float* __restrict__ topk_dist)
{
    int wid  = threadIdx.x >> 6;
    int lane = threadIdx.x & 63;
    int rg   = wid >> 1;
    int hw   = wid & 1;
    int bi0  = id * 4 + rg * 2;
    int b    = bi0 >> 11;
    float inv_sqrt_c = rsqrtf(cc);

    float pi0[16], pi1[16];
    {
        const float4* q0 = (const float4*)(pos + (size_t)bi0 * PD_);
        const float4* q1 = (const float4*)(pos + (size_t)(bi0+1) * PD_);
#pragma unroll
        for (int u = 0; u < 4; u++) {
            float4 a = q0[u];
            pi0[4*u]=a.x; pi0[4*u+1]=a.y; pi0[4*u+2]=a.z; pi0[4*u+3]=a.w;
            float4 e = q1[u];
            pi1[4*u]=e.x; pi1[4*u+1]=e.y; pi1[4*u+2]=e.z; pi1[4*u+3]=e.w;
        }
    }
    float ni0 = 0.f, ni1 = 0.f;
#pragma unroll
    for (int d = 0; d < 16; d++) { ni0 += pi0[d]*pi0[d]; ni1 += pi1[d]*pi1[d]; }
    float om0 = 1.f - cc * ni0;
    float om1 = 1.f - cc * ni1;

    const float* pb = pos + (size_t)b * N_ * PD_;
    int jbase = hw * 1024;
    int j0l   = jbase + lane * 4;

    unsigned rb0[16], rb1[16];
#pragma unroll
    for (int jg = 0; jg < 4; jg++) {
#pragma unroll
        for (int jj = 0; jj < 4; jj++) {
            int j = j0l + jg*256 + jj;
            const float4* pj = (const float4*)(pb + (size_t)j * PD_);
            float4 v0 = pj[0], v1 = pj[1], v2 = pj[2], v3 = pj[3];
            float vv[16] = {v0.x,v0.y,v0.z,v0.w, v1.x,v1.y,v1.z,v1.w,
                            v2.x,v2.y,v2.z,v2.w, v3.x,v3.y,v3.z,v3.w};
            float nj = 0.f, dot0 = 0.f, dot1 = 0.f;
#pragma unroll
            for (int d = 0; d < 16; d++) {
                nj   += vv[d]*vv[d];
                dot0 += pi0[d]*vv[d];
                dot1 += pi1[d]*vv[d];
            }
            float omj   = 1.f - cc * nj;
            float diff0 = ni0 + nj - 2.f*dot0;
            float diff1 = ni1 + nj - 2.f*dot1;
            float den0  = fmaxf(om0 * omj, 1e-8f);
            float den1  = fmaxf(om1 * omj, 1e-8f);
            rb0[jg*4+jj] = __float_as_uint(fmaxf(1.f + 2.f*cc*diff0/den0, 1.f+1e-7f));
            rb1[jg*4+jj] = __float_as_uint(fmaxf(1.f + 2.f*cc*diff1/den1, 1.f+1e-7f));
        }
    }

    // --- common-prefix skip + interleaved radix select for both rows ---
    unsigned T0, T1;
    {
        unsigned band0 = rb0[0], bor0 = rb0[0], band1 = rb1[0], bor1 = rb1[0];
#pragma unroll
        for (int tt = 1; tt < 16; tt++) {
            band0 &= rb0[tt]; bor0 |= rb0[tt];
            band1 &= rb1[tt]; bor1 |= rb1[tt];
        }
#pragma unroll
        for (int off = 32; off; off >>= 1) {
            band0 &= __shfl_xor(band0, off); bor0 |= __shfl_xor(bor0, off);
            band1 &= __shfl_xor(band1, off); bor1 |= __shfl_xor(bor1, off);
        }
        unsigned df0 = band0 ^ bor0, df1 = band1 ^ bor1;
        int hib0 = df0 ? (31 - __clz(df0)) : -1;
        int hib1 = df1 ? (31 - __clz(df1)) : -1;
        int hib  = hib0 > hib1 ? hib0 : hib1;
        T0 = (hib >= 0) ? (band0 & ~((1u << (hib+1)) - 1u)) : band0;
        T1 = (hib >= 0) ? (band1 & ~((1u << (hib+1)) - 1u)) : band1;
        for (int bit = hib; bit >= 0; --bit) {
            unsigned p0 = T0 | (1u << bit), p1 = T1 | (1u << bit);
            int c0 = 0, c1 = 0;
#pragma unroll
            for (int tt = 0; tt < 16; tt++) {
                c0 += __popcll(__ballot(rb0[tt] < p0));
                c1 += __popcll(__ballot(rb1[tt] < p1));
            }
            if (c0 < K_) T0 = p0;
            if (c1 < K_) T1 = p1;
        }
    }
    int cl0 = 0, cl1 = 0;
#pragma unroll
    for (int tt = 0; tt < 16; tt++) {
        cl0 += __popcll(__ballot(rb0[tt] < T0));
        cl1 += __popcll(__ballot(rb1[tt] < T1));
    }

    extract_row(rb0, T0, cl0, K_ - cl0, cand[rg*2+0], hw, jbase, lane);
    extract_row(rb1, T1, cl1, K_ - cl1, cand[rg*2+1], hw, jbase, lane);
    __syncthreads();

    // --- merge: wave w ranks row w's 64 candidates ---
    {
        unsigned long long mykey = cand[wid][lane];
        int rank = 0;
#pragma unroll 8
        for (int M = 0; M < 64; M++)
            rank += (cand[wid][M] < mykey) ? 1 : 0;
        if (rank < K_) {
            int bi = id * 4 + wid;
            topk_idx [(size_t)bi * K_ + rank] = (int)(mykey & 0xffffffffu);
            topk_dist[(size_t)bi * K_ + rank] =
                acoshf(__uint_as_float((unsigned)(mykey >> 32))) * inv_sqrt_c;
        }
    }
}

// ---------------------------------------------------------------------------
// FUSED prep + dist: dist is independent of all weight prep, so its 1024
// blocks run concurrently with transposes/LN1 (prep cost hidden under dist).
// id: [0,1024) dist ; [1024,4096) transposes ; [4096,4102) bias ;
//     [4102,5126) LN1
// ---------------------------------------------------------------------------
__global__ __launch_bounds__(256)
void prep_dist_kernel(const float* __restrict__ Wq, const float* __restrict__ Wk,
                      const float* __restrict__ Wv, const float* __restrict__ Wo,
                      const float* __restrict__ W1, const float* __restrict__ W2,
                      const float* __restrict__ bq, const float* __restrict__ bk,
                      const float* __restrict__ bv,
                      unsigned short* __restrict__ qkvWt,
                      unsigned short* __restrict__ WoT,
                      unsigned short* __restrict__ W1T,
                      unsigned short* __restrict__ W2T,
                      float* __restrict__ qkv_b,
                      const float* __restrict__ pos,
                      const float* __restrict__ c_ptr,
                      int* __restrict__ tk_i, float* __restrict__ tk_d,
                      const float* __restrict__ x,
                      const float* __restrict__ ln1_scale,
                      const float* __restrict__ ln1_bias,
                      unsigned short* __restrict__ xn)
{
    __shared__ __align__(16) char smem_raw[4352];   // max(cand 2KB, tile 4.2KB)
    int id = blockIdx.x;
    int t  = threadIdx.x;

    if (id < 1024) {                  // dist + top-k
        dist_topk_body((unsigned long long (*)[64])smem_raw, id,
                       pos, *c_ptr, tk_i, tk_d);
        return;
    }
    id -= 1024;

    if (id >= 3078) {                 // LN1
        int wave = (id - 3078) * 4 + (t >> 6);
        int lane = t & 63;
        const float* xr = x + (size_t)wave * DIM_;
        float v[8];
        float s = 0.f;
#pragma unroll
        for (int i = 0; i < 8; i++) { v[i] = xr[lane + i*64]; s += v[i]; }
#pragma unroll
        for (int off = 32; off; off >>= 1) s += __shfl_xor(s, off);
        float mean = s * (1.f / DIM_);
        float vs = 0.f;
#pragma unroll
        for (int i = 0; i < 8; i++) { float d = v[i] - mean; vs += d*d; }
#pragma unroll
        for (int off = 32; off; off >>= 1) vs += __shfl_xor(vs, off);
        float inv = rsqrtf(vs * (1.f / DIM_) + 1e-6f);
        unsigned short* yr = xn + (size_t)wave * DIM_;
#pragma unroll
        for (int i = 0; i < 8; i++) {
            int cc = lane + i*64;
            yr[cc] = f2bf((v[i] - mean) * inv * ln1_scale[cc] + ln1_bias[cc]);
        }
        return;
    }
    if (id >= 3072) {                 // bias pack
        int i = (id - 3072) * 256 + t;
        if (i < DIM_)            qkv_b[i] = bq[i];
        else if (i < 2*DIM_)     qkv_b[i] = bk[i - DIM_];
        else                     qkv_b[i] = bv[i - 2*DIM_];
        return;
    }

    const float* W; unsigned short* Wt; int Kd, Nw, nx, ti;
    if      (id < 256)  { W = Wq; Wt = qkvWt;               Kd = 512;  Nw = 512;  nx = 16; ti = id; }
    else if (id < 512)  { W = Wk; Wt = qkvWt + 512*512;     Kd = 512;  Nw = 512;  nx = 16; ti = id - 256; }
    else if (id < 768)  { W = Wv; Wt = qkvWt + 2*512*512;   Kd = 512;  Nw = 512;  nx = 16; ti = id - 512; }
    else if (id < 1024) { W = Wo; Wt = WoT;                 Kd = 512;  Nw = 512;  nx = 16; ti = id - 768; }
    else if (id < 2048) { W = W1; Wt = W1T;                 Kd = 512;  Nw = 2048; nx = 64; ti = id - 1024; }
    else                { W = W2; Wt = W2T;                 Kd = 2048; Nw = 512;  nx = 16; ti = id - 2048; }

    float (*tile)[33] = (float (*)[33])smem_raw;
    int n0 = (ti % nx) * 32, k0 = (ti / nx) * 32;
    int tx = t & 31, ty = t >> 5;
#pragma unroll
    for (int i = 0; i < 32; i += 8)
        tile[ty + i][tx] = W[(size_t)(k0 + ty + i) * Nw + n0 + tx];
    __syncthreads();
#pragma unroll
    for (int i = 0; i < 32; i += 8)
        Wt[(size_t)(n0 + ty + i) * Kd + k0 + tx] = f2bf(tile[tx][ty + i]);
}

// ---------------------------------------------------------------------------
// LayerNorm standalone (LN2)
// ---------------------------------------------------------------------------
__global__ void layernorm_kernel(const float* __restrict__ x,
                                 const float* __restrict__ scale,
                                 const float* __restrict__ bias,
                                 unsigned short* __restrict__ y)
{
    int wave = (blockIdx.x * blockDim.x + threadIdx.x) >> 6;
    int lane = threadIdx.x & 63;
    if (wave >= TOK_) return;
    const float* xr = x + (size_t)wave * DIM_;
    float v[8];
    float s = 0.f;
#pragma unroll
    for (int i = 0; i < 8; i++) { v[i] = xr[lane + i*64]; s += v[i]; }
#pragma unroll
    for (int off = 32; off; off >>= 1) s += __shfl_xor(s, off);
    float mean = s * (1.f / DIM_);
    float vs = 0.f;
#pragma unroll
    for (int i = 0; i < 8; i++) { float d = v[i] - mean; vs += d*d; }
#pragma unroll
    for (int off = 32; off; off >>= 1) vs += __shfl_xor(vs, off);
    float inv = rsqrtf(vs * (1.f / DIM_) + 1e-6f);
    unsigned short* yr = y + (size_t)wave * DIM_;
#pragma unroll
    for (int i = 0; i < 8; i++) {
        int c = lane + i*64;
        yr[c] = f2bf((v[i] - mean) * inv * scale[c] + bias[c]);
    }
}

// ---------------------------------------------------------------------------
// Sparse attention with bf16 K/V. One wave per (b,h,i).
// ---------------------------------------------------------------------------
__global__ __launch_bounds__(256)
void attn_kernel(const float* __restrict__ q,
                 const unsigned short* __restrict__ kv,
                 const int* __restrict__ topk_idx, const float* __restrict__ topk_dist,
                 const float* __restrict__ log_tau_p, const float* __restrict__ attn_scale_p,
                 unsigned int* __restrict__ out)   // bf16 pairs
{
    int gw   = (blockIdx.x * blockDim.x + threadIdx.x) >> 6;
    int lane = threadIdx.x & 63;
    if (gw >= B_ * NH_ * N_) return;
    int b = gw / (NH_ * N_);
    int r = gw % (NH_ * N_);
    int h = r / N_;
    int i = r % N_;
    int tok = b * N_ + i;

    float tau    = fmaxf(__expf(*log_tau_p), 1e-8f);
    float ascale = *attn_scale_p;

    const int*   idxp = topk_idx  + (size_t)tok * K_;
    const float* dstp = topk_dist + (size_t)tok * K_;
    int   my_idx  = idxp[lane & 31];
    float my_dist = dstp[lane & 31];

    int jj   = lane >> 1;
    int half = lane & 1;

    // q half: 32 floats
    const float4* qp = (const float4*)(q + (size_t)tok * DIM_ + h * HD_ + half * 32);
    float4 qv[8];
#pragma unroll
    for (int u = 0; u < 8; u++) qv[u] = qp[u];

    // k half (bf16): 32 shorts = 4 x 16B
    int nb = __shfl(my_idx, jj);
    const uint4* kp = (const uint4*)(kv + (size_t)(b * N_ + nb) * KV_ + h * HD_ + half * 32);
    float dot = 0.f;
#pragma unroll
    for (int u = 0; u < 4; u++) {
        uint4 kw = kp[u];
        dot += qv[2*u].x   * bflo(kw.x) + qv[2*u].y   * bfhi(kw.x)
             + qv[2*u].z   * bflo(kw.y) + qv[2*u].w   * bfhi(kw.y)
             + qv[2*u+1].x * bflo(kw.z) + qv[2*u+1].y * bfhi(kw.z)
             + qv[2*u+1].z * bflo(kw.w) + qv[2*u+1].w * bfhi(kw.w);
    }
    dot += __shfl_xor(dot, 1);   // full dot on both lanes of the pair

    float fs = dot * 0.125f;                        // 1/sqrt(64)
    float gs = -__shfl(my_dist, jj) / tau;
    float s  = ascale * tanh_fast(fs + gs);

    // softmax over the 32 scores (each duplicated on a lane pair)
    float mx = s;
#pragma unroll
    for (int off = 32; off; off >>= 1) mx = fmaxf(mx, __shfl_xor(mx, off));
    float e  = __expf(s - mx);
    float ec = half ? 0.f : e;
#pragma unroll
    for (int off = 32; off; off >>= 1) ec += __shfl_xor(ec, off);
    float inv = 1.f / ec;

    // V phase: dim pair d2 = 2*(lane&31); lane>=32 handles odd neighbors
    int dp    = lane & 31;
    int half2 = lane >> 5;
    const unsigned int* vb = (const unsigned int*)(kv + DIM_ + h * HD_) + dp;
    float ax = 0.f, ay = 0.f;
#pragma unroll
    for (int it = 0; it < 16; it++) {
        int t2 = half2 + 2*it;
        float w  = __shfl(e, t2 * 2) * inv;
        int   nj = __shfl(my_idx, t2);
        unsigned vv = vb[(size_t)(b * N_ + nj) * (KV_/2)];
        ax += w * bflo(vv);
        ay += w * bfhi(vv);
    }
    ax += __shfl_xor(ax, 32);
    ay += __shfl_xor(ay, 32);
    if (lane < 32) {
        unsigned pck = ((unsigned)f2bf(ay) << 16) | (unsigned)f2bf(ax);
        out[(size_t)tok * (DIM_/2) + h * (HD_/2) + dp] = pck;
    }
}

// ---------------------------------------------------------------------------
extern "C" void kernel_launch(void* const* d_in, const int* in_sizes, int n_in,
                              void* d_out, int out_size, void* d_ws, size_t ws_size,
                              hipStream_t stream)
{
    const float* x          = (const float*)d_in[0];
    const float* positions  = (const float*)d_in[1];
    const float* c_p        = (const float*)d_in[2];
    const float* Wq         = (const float*)d_in[3];
    const float* bq         = (const float*)d_in[4];
    const float* Wk         = (const float*)d_in[5];
    const float* bk         = (const float*)d_in[6];
    const float* Wv         = (const float*)d_in[7];
    const float* bv         = (const float*)d_in[8];
    const float* Wo         = (const float*)d_in[9];
    const float* bo         = (const float*)d_in[10];
    const float* W1         = (const float*)d_in[11];
    const float* b1         = (const float*)d_in[12];
    const float* W2         = (const float*)d_in[13];
    const float* b2         = (const float*)d_in[14];
    const float* ln1_scale  = (const float*)d_in[15];
    const float* ln1_bias   = (const float*)d_in[16];
    const float* ln2_scale  = (const float*)d_in[17];
    const float* ln2_bias   = (const float*)d_in[18];
    const float* log_tau    = (const float*)d_in[19];
    const float* attn_scale = (const float*)d_in[20];

    char* p = (char*)d_ws;
    unsigned short* qkvWt  = (unsigned short*)p; p += (size_t)QKV_ * DIM_ * 2;   // [1536][512] bf16
    unsigned short* WoT    = (unsigned short*)p; p += (size_t)DIM_ * DIM_ * 2;   // [512][512]
    unsigned short* W1T    = (unsigned short*)p; p += (size_t)FFN_ * DIM_ * 2;   // [2048][512]
    unsigned short* W2T    = (unsigned short*)p; p += (size_t)DIM_ * FFN_ * 2;   // [512][2048]
    float*          qkv_b  = (float*)p;          p += (size_t)QKV_ * 4;
    unsigned short* xn     = (unsigned short*)p; p += (size_t)TOK_ * DIM_ * 2;   // bf16
    float*          qf     = (float*)p;          p += (size_t)TOK_ * DIM_ * 4;   // fp32 q
    unsigned short* kvb    = (unsigned short*)p; p += (size_t)TOK_ * KV_ * 2;    // bf16 k|v
    unsigned short* attn_o = (unsigned short*)p; p += (size_t)TOK_ * DIM_ * 2;   // bf16
    float*          x1     = (float*)p;          p += (size_t)TOK_ * DIM_ * 4;
    unsigned short* x2n    = (unsigned short*)p; p += (size_t)TOK_ * DIM_ * 2;
    unsigned short* hbuf   = (unsigned short*)p; p += (size_t)TOK_ * FFN_ * 2;
    float*          tk_d   = (float*)p;          p += (size_t)TOK_ * K_ * 4;
    int*            tk_i   = (int*)p;            p += (size_t)TOK_ * K_ * 4;

    // --- fused prep + dist: dist (1024) || transposes (3072) + bias + LN1 ---
    prep_dist_kernel<<<5126, 256, 0, stream>>>(Wq, Wk, Wv, Wo, W1, W2,
                                               bq, bk, bv,
                                               qkvWt, WoT, W1T, W2T, qkv_b,
                                               positions, c_p, tk_i, tk_d,
                                               x, ln1_scale, ln1_bias, xn);

    // --- QKV GEMM: 64x128 tiles -> 768 blocks ---
    gemm_bf16_kernel<3,64,128><<<dim3(QKV_/128, TOK_/64), 256, 0, stream>>>(
        xn, qkvWt, qkv_b, nullptr, qf, kvb, QKV_, DIM_);

    // --- sparse attention -> bf16 ---
    attn_kernel<<<(B_*NH_*N_)/4, 256, 0, stream>>>(qf, kvb, tk_i, tk_d,
                                                   log_tau, attn_scale,
                                                   (unsigned int*)attn_o);

    // --- x1 = x + attn_o @ Wo + bo (fp32), 64x64 -> 512 blocks ---
    gemm_bf16_kernel<1,64,64><<<dim3(DIM_/64, TOK_/64), 256, 0, stream>>>(
        attn_o, WoT, bo, x, x1, nullptr, DIM_, DIM_);

    // --- LN2 -> bf16 ---
    layernorm_kernel<<<TOK_/4, 256, 0, stream>>>(x1, ln2_scale, ln2_bias, x2n);

    // --- FFN1: gelu(x2n @ W1 + b1) -> bf16 h, 64x128 -> 1024 blocks ---
    gemm_bf16_kernel<2,64,128><<<dim3(FFN_/128, TOK_/64), 256, 0, stream>>>(
        x2n, W1T, b1, nullptr, nullptr, hbuf, FFN_, DIM_);

    // --- FFN2: out = x1 + h @ W2 + b2 (fp32), 64x64 -> 512 blocks ---
    gemm_bf16_kernel<1,64,64><<<dim3(DIM_/64, TOK_/64), 256, 0, stream>>>(
        hbuf, W2T, b2, x1, (float*)d_out, nullptr, DIM_, FFN_);
}

// Round 13
// 244.409 us; speedup vs baseline: 1.4743x; 1.4743x over previous
//
#include <hip/hip_runtime.h>
#include <math.h>

#define B_   2
#define N_   2048
#define DIM_ 512
#define NH_  8
#define HD_  64
#define K_   32
#define PD_  16
#define TOK_ (B_*N_)     // 4096 rows
#define FFN_ 2048
#define QKV_ (3*DIM_)    // 1536
#define KV_  1024        // k|v bf16 row length

typedef __bf16 bf16x8 __attribute__((ext_vector_type(8)));
typedef float  f32x4  __attribute__((ext_vector_type(4)));

__device__ __forceinline__ unsigned short f2bf(float f) {
    unsigned int u = __float_as_uint(f);
    u = (u + 0x7fffu + ((u >> 16) & 1u)) >> 16;
    return (unsigned short)u;
}

__device__ __forceinline__ float bflo(unsigned u) { return __uint_as_float(u << 16); }
__device__ __forceinline__ float bfhi(unsigned u) { return __uint_as_float(u & 0xffff0000u); }

__device__ __forceinline__ float gelu_tanh(float x) {
    float x3 = x * x * x;
    return 0.5f * x * (1.f + tanhf(0.7978845608028654f * (x + 0.044715f * x3)));
}

__device__ __forceinline__ float tanh_fast(float x) {
    float e = __expf(2.f * x);
    return 1.f - 2.f / (e + 1.f);
}

__device__ __forceinline__ int lane_mbcnt(unsigned long long m) {
    return __builtin_amdgcn_mbcnt_hi((unsigned)(m >> 32),
           __builtin_amdgcn_mbcnt_lo((unsigned)m, 0));
}

// async global->LDS, 16B per lane. LDS dst must be wave-uniform base + lane*16.
#define GLOAD_LDS16(g, l) __builtin_amdgcn_global_load_lds(                        \
    (const __attribute__((address_space(1))) unsigned int*)(const void*)(g),       \
    (__attribute__((address_space(3))) unsigned int*)(void*)(l), 16, 0, 0)

// ---------------------------------------------------------------------------
// GEMM: C[M,N] = A[M,Kd] @ Bt[N,Kd]^T, BK=64, 8-chunk XOR swizzle (0 bank
// conflicts, staging lane-ordered for global_load_lds). 256 thr, 4 waves 2x2.
// DOUBLE-BUFFERED LDS: per iteration — barrier, stage(next buf), compute(cur).
// The vmcnt(0) drain at iteration i+1's barrier waits on loads issued a full
// compute-phase earlier -> global latency hidden inside the block; one
// barrier per K-iter instead of two.
// EPI: 0 +bias->fp32 ; 1 +bias+res->fp32 ; 2 gelu(+bias)->bf16
//      3 QKV split: col<512 -> q fp32; col>=512 -> kv bf16 [row][1024]
// ---------------------------------------------------------------------------
template<int EPI, int BM, int BN>
__global__ __launch_bounds__(256)
void gemm_bf16_kernel(const unsigned short* __restrict__ A,
                      const unsigned short* __restrict__ Bt,
                      const float* __restrict__ bias,
                      const float* __restrict__ res,
                      float* __restrict__ Cf,
                      unsigned short* __restrict__ Cb,
                      int N, int Kd)
{
    constexpr int WM = BM / 2;
    constexpr int WN = BN / 2;
    constexpr int FM = WM / 16;
    constexpr int FN = WN / 16;
    constexpr int BUFSZ = (BM + BN) * 64;

    __shared__ __align__(16) unsigned short smem[2 * BUFSZ];

    int t    = threadIdx.x;
    int lane = t & 63;
    int wid  = t >> 6;
    int wm   = wid >> 1, wn = wid & 1;
    int bm0  = blockIdx.y * BM;
    int bn0  = blockIdx.x * BN;
    int quad = lane >> 4;
    int rlo  = lane & 15;

    f32x4 acc[FM][FN] = {};

    auto stage = [&](int buf, int k0) {
        unsigned short* As_ = smem + buf * BUFSZ;
        unsigned short* Bs_ = As_ + BM * 64;
#pragma unroll
        for (int l = 0; l < BM/32; l++) {
            int idx = l*256 + t;
            int r   = idx >> 3;
            int g   = (idx & 7) ^ (r & 7);
            GLOAD_LDS16(A + (size_t)(bm0 + r) * Kd + k0 + g*8, As_ + idx*8);
        }
#pragma unroll
        for (int l = 0; l < BN/32; l++) {
            int idx = l*256 + t;
            int r   = idx >> 3;
            int g   = (idx & 7) ^ (r & 7);
            GLOAD_LDS16(Bt + (size_t)(bn0 + r) * Kd + k0 + g*8, Bs_ + idx*8);
        }
    };

    auto compute = [&](int buf) {
        unsigned short* As_ = smem + buf * BUFSZ;
        unsigned short* Bs_ = As_ + BM * 64;
        bf16x8 af[FM][2], bfr[FN][2];
#pragma unroll
        for (int mi = 0; mi < FM; mi++) {
            int r = wm*WM + mi*16 + rlo;
#pragma unroll
            for (int s = 0; s < 2; s++)
                af[mi][s] = *(const bf16x8*)(As_ + r*64 + ((s*4 + quad) ^ (r & 7))*8);
        }
#pragma unroll
        for (int ni = 0; ni < FN; ni++) {
            int r = wn*WN + ni*16 + rlo;
#pragma unroll
            for (int s = 0; s < 2; s++)
                bfr[ni][s] = *(const bf16x8*)(Bs_ + r*64 + ((s*4 + quad) ^ (r & 7))*8);
        }
#pragma unroll
        for (int s = 0; s < 2; s++)
#pragma unroll
            for (int mi = 0; mi < FM; mi++)
#pragma unroll
                for (int ni = 0; ni < FN; ni++)
                    acc[mi][ni] = __builtin_amdgcn_mfma_f32_16x16x32_bf16(
                        af[mi][s], bfr[ni][s], acc[mi][ni], 0, 0, 0);
    };

    stage(0, 0);
    int buf = 0;
    for (int k0 = 0; k0 < Kd; k0 += 64) {
        __syncthreads();                       // drains stage(cur); also fences
        if (k0 + 64 < Kd) stage(buf ^ 1, k0 + 64);   // prefetch next tile
        compute(buf);                          // overlap with prefetch in flight
        buf ^= 1;
    }

    // epilogue: D row = quad*4 + r, col = rlo within each 16x16 tile
#pragma unroll
    for (int mi = 0; mi < FM; mi++) {
#pragma unroll
        for (int ni = 0; ni < FN; ni++) {
            int col = bn0 + wn*WN + ni*16 + rlo;
            float bv = bias[col];
#pragma unroll
            for (int r = 0; r < 4; r++) {
                int row = bm0 + wm*WM + mi*16 + quad*4 + r;
                float val = acc[mi][ni][r] + bv;
                if (EPI == 1) val += res[(size_t)row * N + col];
                if (EPI == 2) {
                    val = gelu_tanh(val);
                    Cb[(size_t)row * N + col] = f2bf(val);
                } else if (EPI == 3) {
                    if (col < DIM_) Cf[(size_t)row * DIM_ + col] = val;
                    else            Cb[(size_t)row * KV_ + (col - DIM_)] = f2bf(val);
                } else {
                    Cf[(size_t)row * N + col] = val;
                }
            }
        }
    }
}

// ---------------------------------------------------------------------------
// top-K extraction helper: lt pass (order irrelevant; merge re-ranks) + eq
// pass in ascending-j order (exact jax.lax.top_k lower-index-first).
// ---------------------------------------------------------------------------
__device__ __forceinline__ void extract_row(const unsigned* rb, unsigned T,
                                            int cnt_lt, int m,
                                            unsigned long long* crow,
                                            int hw, int jbase, int lane)
{
    int ltpos = 0;
#pragma unroll
    for (int tt = 0; tt < 16; tt++) {
        bool is_lt = rb[tt] < T;
        unsigned long long mlt = __ballot(is_lt);
        int p = ltpos + lane_mbcnt(mlt);
        if (is_lt) {
            int j = jbase + (tt >> 2)*256 + lane*4 + (tt & 3);
            crow[hw*K_ + p] = ((unsigned long long)rb[tt] << 32) | (unsigned)j;
        }
        ltpos += __popcll(mlt);
    }
    int eqpos = 0;
#pragma unroll
    for (int jg = 0; jg < 4; jg++) {
        bool iseq[4]; unsigned long long meq[4]; int bel[4];
#pragma unroll
        for (int jj = 0; jj < 4; jj++) {
            iseq[jj] = (rb[jg*4+jj] == T);
            meq[jj]  = __ballot(iseq[jj]);
            bel[jj]  = lane_mbcnt(meq[jj]);
        }
        int lane_prefix = bel[0] + bel[1] + bel[2] + bel[3];
        int within = 0;
#pragma unroll
        for (int jj = 0; jj < 4; jj++) {
            int p = eqpos + lane_prefix + within;
            if (iseq[jj] && p < m) {
                int j = jbase + jg*256 + lane*4 + jj;
                crow[hw*K_ + cnt_lt + p] =
                    ((unsigned long long)rb[jg*4+jj] << 32) | (unsigned)j;
            }
            within += iseq[jj] ? 1 : 0;
        }
        eqpos += __popcll(meq[0]) + __popcll(meq[1]) + __popcll(meq[2]) + __popcll(meq[3]);
    }
}

// ---------------------------------------------------------------------------
// Poincare dist + exact top-K (standalone — R11's measured-best, 43.7us).
// Block = 4 rows (one batch), 4 waves. Wave (rg, hw): rows {2rg, 2rg+1} over
// j-half hw*1024. Each posT float4 feeds both pivots (L2 traffic halved);
// 2-row radix selections interleaved in one probe loop. Merge: wave w ranks
// row w's 64 candidates by packed (rb,j) u64 key.
// ---------------------------------------------------------------------------
__global__ __launch_bounds__(256)
void dist_topk_kernel(const float* __restrict__ pos,
                      const float* __restrict__ posT,
                      const float* __restrict__ pos_sq,
                      const float* __restrict__ c_ptr,
                      int* __restrict__ topk_idx, float* __restrict__ topk_dist)
{
    __shared__ unsigned long long cand[4][64];

    int wid  = threadIdx.x >> 6;      // 0..3
    int lane = threadIdx.x & 63;
    int rg   = wid >> 1;              // row-pair group
    int hw   = wid & 1;               // j-half
    int bi0  = blockIdx.x * 4 + rg * 2;
    int b    = bi0 >> 11;             // all 4 rows of a block share the batch
    float c  = *c_ptr;
    float inv_sqrt_c = rsqrtf(c);

    float pi0[16], pi1[16];
    {
        const float4* q0 = (const float4*)(pos + (size_t)bi0 * PD_);
        const float4* q1 = (const float4*)(pos + (size_t)(bi0+1) * PD_);
#pragma unroll
        for (int u = 0; u < 4; u++) {
            float4 a = q0[u];
            pi0[4*u]=a.x; pi0[4*u+1]=a.y; pi0[4*u+2]=a.z; pi0[4*u+3]=a.w;
            float4 e = q1[u];
            pi1[4*u]=e.x; pi1[4*u+1]=e.y; pi1[4*u+2]=e.z; pi1[4*u+3]=e.w;
        }
    }
    float om0 = 1.f - c * pos_sq[bi0];
    float om1 = 1.f - c * pos_sq[bi0+1];

    const float* pT  = posT + (size_t)b * 16 * N_;
    const float* sqb = pos_sq + b * N_;
    int jbase = hw * 1024;
    int j0l   = jbase + lane * 4;

    unsigned rb0[16], rb1[16];
#pragma unroll
    for (int jg = 0; jg < 4; jg++) {
        int j0 = j0l + jg * 256;
        float ax=0,ay=0,az=0,aw=0, bx=0,by=0,bz=0,bw=0;
#pragma unroll
        for (int d = 0; d < 16; d++) {
            float4 v = *(const float4*)(pT + d * N_ + j0);
            float d0x = pi0[d]-v.x, d0y = pi0[d]-v.y, d0z = pi0[d]-v.z, d0w = pi0[d]-v.w;
            ax += d0x*d0x; ay += d0y*d0y; az += d0z*d0z; aw += d0w*d0w;
            float d1x = pi1[d]-v.x, d1y = pi1[d]-v.y, d1z = pi1[d]-v.z, d1w = pi1[d]-v.w;
            bx += d1x*d1x; by += d1y*d1y; bz += d1z*d1z; bw += d1w*d1w;
        }
        float4 sq = *(const float4*)(sqb + j0);
        float da[4]={ax,ay,az,aw}, db[4]={bx,by,bz,bw}, sqa[4]={sq.x,sq.y,sq.z,sq.w};
#pragma unroll
        for (int jj = 0; jj < 4; jj++) {
            float omj  = 1.f - c * sqa[jj];
            float den0 = fmaxf(om0 * omj, 1e-8f);
            float den1 = fmaxf(om1 * omj, 1e-8f);
            rb0[jg*4+jj] = __float_as_uint(fmaxf(1.f + 2.f*c*da[jj]/den0, 1.f+1e-7f));
            rb1[jg*4+jj] = __float_as_uint(fmaxf(1.f + 2.f*c*db[jj]/den1, 1.f+1e-7f));
        }
    }

    // --- common-prefix skip + interleaved radix select for both rows ---
    unsigned T0, T1;
    {
        unsigned band0 = rb0[0], bor0 = rb0[0], band1 = rb1[0], bor1 = rb1[0];
#pragma unroll
        for (int tt = 1; tt < 16; tt++) {
            band0 &= rb0[tt]; bor0 |= rb0[tt];
            band1 &= rb1[tt]; bor1 |= rb1[tt];
        }
#pragma unroll
        for (int off = 32; off; off >>= 1) {
            band0 &= __shfl_xor(band0, off); bor0 |= __shfl_xor(bor0, off);
            band1 &= __shfl_xor(band1, off); bor1 |= __shfl_xor(bor1, off);
        }
        unsigned df0 = band0 ^ bor0, df1 = band1 ^ bor1;
        int hib0 = df0 ? (31 - __clz(df0)) : -1;
        int hib1 = df1 ? (31 - __clz(df1)) : -1;
        int hib  = hib0 > hib1 ? hib0 : hib1;
        T0 = (hib >= 0) ? (band0 & ~((1u << (hib+1)) - 1u)) : band0;
        T1 = (hib >= 0) ? (band1 & ~((1u << (hib+1)) - 1u)) : band1;
        for (int bit = hib; bit >= 0; --bit) {
            unsigned p0 = T0 | (1u << bit), p1 = T1 | (1u << bit);
            int c0 = 0, c1 = 0;
#pragma unroll
            for (int tt = 0; tt < 16; tt++) {
                c0 += __popcll(__ballot(rb0[tt] < p0));
                c1 += __popcll(__ballot(rb1[tt] < p1));
            }
            if (c0 < K_) T0 = p0;
            if (c1 < K_) T1 = p1;
        }
    }
    int cl0 = 0, cl1 = 0;
#pragma unroll
    for (int tt = 0; tt < 16; tt++) {
        cl0 += __popcll(__ballot(rb0[tt] < T0));
        cl1 += __popcll(__ballot(rb1[tt] < T1));
    }

    extract_row(rb0, T0, cl0, K_ - cl0, cand[rg*2+0], hw, jbase, lane);
    extract_row(rb1, T1, cl1, K_ - cl1, cand[rg*2+1], hw, jbase, lane);
    __syncthreads();

    // --- merge: wave w ranks row w's 64 candidates ---
    {
        unsigned long long mykey = cand[wid][lane];
        int rank = 0;
#pragma unroll 8
        for (int M = 0; M < 64; M++)
            rank += (cand[wid][M] < mykey) ? 1 : 0;
        if (rank < K_) {
            int bi = blockIdx.x * 4 + wid;
            topk_idx [(size_t)bi * K_ + rank] = (int)(mykey & 0xffffffffu);
            topk_dist[(size_t)bi * K_ + rank] =
                acoshf(__uint_as_float((unsigned)(mykey >> 32))) * inv_sqrt_c;
        }
    }
}

// ---------------------------------------------------------------------------
// FUSED prep (VGPR-light branches only): 6 weight transposes + bias3 pack +
// pos_sq/posT + LN1.
// id: [0,3072) transposes ; [3072,3078) bias ; [3078,3094) pos ; [3094,4118) LN1
// ---------------------------------------------------------------------------
__global__ void fused_prep_kernel(const float* __restrict__ Wq, const float* __restrict__ Wk,
                            const float* __restrict__ Wv, const float* __restrict__ Wo,
                            const float* __restrict__ W1, const float* __restrict__ W2,
                            const float* __restrict__ bq, const float* __restrict__ bk,
                            const float* __restrict__ bv,
                            unsigned short* __restrict__ qkvWt,
                            unsigned short* __restrict__ WoT,
                            unsigned short* __restrict__ W1T,
                            unsigned short* __restrict__ W2T,
                            float* __restrict__ qkv_b,
                            const float* __restrict__ pos,
                            float* __restrict__ pos_sq,
                            float* __restrict__ posT,
                            const float* __restrict__ x,
                            const float* __restrict__ ln1_scale,
                            const float* __restrict__ ln1_bias,
                            unsigned short* __restrict__ xn)
{
    int id = blockIdx.x;
    int t  = threadIdx.x;

    if (id >= 3094) {                 // LN1
        int wave = (id - 3094) * 4 + (t >> 6);
        int lane = t & 63;
        const float* xr = x + (size_t)wave * DIM_;
        float v[8];
        float s = 0.f;
#pragma unroll
        for (int i = 0; i < 8; i++) { v[i] = xr[lane + i*64]; s += v[i]; }
#pragma unroll
        for (int off = 32; off; off >>= 1) s += __shfl_xor(s, off);
        float mean = s * (1.f / DIM_);
        float vs = 0.f;
#pragma unroll
        for (int i = 0; i < 8; i++) { float d = v[i] - mean; vs += d*d; }
#pragma unroll
        for (int off = 32; off; off >>= 1) vs += __shfl_xor(vs, off);
        float inv = rsqrtf(vs * (1.f / DIM_) + 1e-6f);
        unsigned short* yr = xn + (size_t)wave * DIM_;
#pragma unroll
        for (int i = 0; i < 8; i++) {
            int cc = lane + i*64;
            yr[cc] = f2bf((v[i] - mean) * inv * ln1_scale[cc] + ln1_bias[cc]);
        }
        return;
    }
    if (id >= 3078) {                 // pos_sq + posT
        int i = (id - 3078) * 256 + t;
        int b = i >> 11, j = i & (N_ - 1);
        const float4* p = (const float4*)(pos + (size_t)i * PD_);
        float4 a0 = p[0], a1 = p[1], a2 = p[2], a3 = p[3];
        float pv[16] = {a0.x,a0.y,a0.z,a0.w, a1.x,a1.y,a1.z,a1.w,
                        a2.x,a2.y,a2.z,a2.w, a3.x,a3.y,a3.z,a3.w};
        float s = 0.f;
#pragma unroll
        for (int d = 0; d < 16; d++) s += pv[d]*pv[d];
        pos_sq[i] = s;
        float* pT = posT + (size_t)b * 16 * N_;
#pragma unroll
        for (int d = 0; d < 16; d++) pT[d * N_ + j] = pv[d];
        return;
    }
    if (id >= 3072) {                 // bias pack
        int i = (id - 3072) * 256 + t;
        if (i < DIM_)            qkv_b[i] = bq[i];
        else if (i < 2*DIM_)     qkv_b[i] = bk[i - DIM_];
        else                     qkv_b[i] = bv[i - 2*DIM_];
        return;
    }

    const float* W; unsigned short* Wt; int Kd, Nw, nx, ti;
    if      (id < 256)  { W = Wq; Wt = qkvWt;               Kd = 512;  Nw = 512;  nx = 16; ti = id; }
    else if (id < 512)  { W = Wk; Wt = qkvWt + 512*512;     Kd = 512;  Nw = 512;  nx = 16; ti = id - 256; }
    else if (id < 768)  { W = Wv; Wt = qkvWt + 2*512*512;   Kd = 512;  Nw = 512;  nx = 16; ti = id - 512; }
    else if (id < 1024) { W = Wo; Wt = WoT;                 Kd = 512;  Nw = 512;  nx = 16; ti = id - 768; }
    else if (id < 2048) { W = W1; Wt = W1T;                 Kd = 512;  Nw = 2048; nx = 64; ti = id - 1024; }
    else                { W = W2; Wt = W2T;                 Kd = 2048; Nw = 512;  nx = 16; ti = id - 2048; }

    __shared__ float tile[32][33];
    int n0 = (ti % nx) * 32, k0 = (ti / nx) * 32;
    int tx = t & 31, ty = t >> 5;
#pragma unroll
    for (int i = 0; i < 32; i += 8)
        tile[ty + i][tx] = W[(size_t)(k0 + ty + i) * Nw + n0 + tx];
    __syncthreads();
#pragma unroll
    for (int i = 0; i < 32; i += 8)
        Wt[(size_t)(n0 + ty + i) * Kd + k0 + tx] = f2bf(tile[tx][ty + i]);
}

// ---------------------------------------------------------------------------
// LayerNorm standalone (LN2)
// ---------------------------------------------------------------------------
__global__ void layernorm_kernel(const float* __restrict__ x,
                                 const float* __restrict__ scale,
                                 const float* __restrict__ bias,
                                 unsigned short* __restrict__ y)
{
    int wave = (blockIdx.x * blockDim.x + threadIdx.x) >> 6;
    int lane = threadIdx.x & 63;
    if (wave >= TOK_) return;
    const float* xr = x + (size_t)wave * DIM_;
    float v[8];
    float s = 0.f;
#pragma unroll
    for (int i = 0; i < 8; i++) { v[i] = xr[lane + i*64]; s += v[i]; }
#pragma unroll
    for (int off = 32; off; off >>= 1) s += __shfl_xor(s, off);
    float mean = s * (1.f / DIM_);
    float vs = 0.f;
#pragma unroll
    for (int i = 0; i < 8; i++) { float d = v[i] - mean; vs += d*d; }
#pragma unroll
    for (int off = 32; off; off >>= 1) vs += __shfl_xor(vs, off);
    float inv = rsqrtf(vs * (1.f / DIM_) + 1e-6f);
    unsigned short* yr = y + (size_t)wave * DIM_;
#pragma unroll
    for (int i = 0; i < 8; i++) {
        int c = lane + i*64;
        yr[c] = f2bf((v[i] - mean) * inv * scale[c] + bias[c]);
    }
}

// ---------------------------------------------------------------------------
// Sparse attention with bf16 K/V. One wave per (b,h,i).
// ---------------------------------------------------------------------------
__global__ __launch_bounds__(256)
void attn_kernel(const float* __restrict__ q,
                 const unsigned short* __restrict__ kv,
                 const int* __restrict__ topk_idx, const float* __restrict__ topk_dist,
                 const float* __restrict__ log_tau_p, const float* __restrict__ attn_scale_p,
                 unsigned int* __restrict__ out)   // bf16 pairs
{
    int gw   = (blockIdx.x * blockDim.x + threadIdx.x) >> 6;
    int lane = threadIdx.x & 63;
    if (gw >= B_ * NH_ * N_) return;
    int b = gw / (NH_ * N_);
    int r = gw % (NH_ * N_);
    int h = r / N_;
    int i = r % N_;
    int tok = b * N_ + i;

    float tau    = fmaxf(__expf(*log_tau_p), 1e-8f);
    float ascale = *attn_scale_p;

    const int*   idxp = topk_idx  + (size_t)tok * K_;
    const float* dstp = topk_dist + (size_t)tok * K_;
    int   my_idx  = idxp[lane & 31];
    float my_dist = dstp[lane & 31];

    int jj   = lane >> 1;
    int half = lane & 1;

    // q half: 32 floats
    const float4* qp = (const float4*)(q + (size_t)tok * DIM_ + h * HD_ + half * 32);
    float4 qv[8];
#pragma unroll
    for (int u = 0; u < 8; u++) qv[u] = qp[u];

    // k half (bf16): 32 shorts = 4 x 16B
    int nb = __shfl(my_idx, jj);
    const uint4* kp = (const uint4*)(kv + (size_t)(b * N_ + nb) * KV_ + h * HD_ + half * 32);
    float dot = 0.f;
#pragma unroll
    for (int u = 0; u < 4; u++) {
        uint4 kw = kp[u];
        dot += qv[2*u].x   * bflo(kw.x) + qv[2*u].y   * bfhi(kw.x)
             + qv[2*u].z   * bflo(kw.y) + qv[2*u].w   * bfhi(kw.y)
             + qv[2*u+1].x * bflo(kw.z) + qv[2*u+1].y * bfhi(kw.z)
             + qv[2*u+1].z * bflo(kw.w) + qv[2*u+1].w * bfhi(kw.w);
    }
    dot += __shfl_xor(dot, 1);   // full dot on both lanes of the pair

    float fs = dot * 0.125f;                        // 1/sqrt(64)
    float gs = -__shfl(my_dist, jj) / tau;
    float s  = ascale * tanh_fast(fs + gs);

    // softmax over the 32 scores (each duplicated on a lane pair)
    float mx = s;
#pragma unroll
    for (int off = 32; off; off >>= 1) mx = fmaxf(mx, __shfl_xor(mx, off));
    float e  = __expf(s - mx);
    float ec = half ? 0.f : e;
#pragma unroll
    for (int off = 32; off; off >>= 1) ec += __shfl_xor(ec, off);
    float inv = 1.f / ec;

    // V phase: dim pair d2 = 2*(lane&31); lane>=32 handles odd neighbors
    int dp    = lane & 31;
    int half2 = lane >> 5;
    const unsigned int* vb = (const unsigned int*)(kv + DIM_ + h * HD_) + dp;
    float ax = 0.f, ay = 0.f;
#pragma unroll
    for (int it = 0; it < 16; it++) {
        int t2 = half2 + 2*it;
        float w  = __shfl(e, t2 * 2) * inv;
        int   nj = __shfl(my_idx, t2);
        unsigned vv = vb[(size_t)(b * N_ + nj) * (KV_/2)];
        ax += w * bflo(vv);
        ay += w * bfhi(vv);
    }
    ax += __shfl_xor(ax, 32);
    ay += __shfl_xor(ay, 32);
    if (lane < 32) {
        unsigned pck = ((unsigned)f2bf(ay) << 16) | (unsigned)f2bf(ax);
        out[(size_t)tok * (DIM_/2) + h * (HD_/2) + dp] = pck;
    }
}

// ---------------------------------------------------------------------------
extern "C" void kernel_launch(void* const* d_in, const int* in_sizes, int n_in,
                              void* d_out, int out_size, void* d_ws, size_t ws_size,
                              hipStream_t stream)
{
    const float* x          = (const float*)d_in[0];
    const float* positions  = (const float*)d_in[1];
    const float* c_p        = (const float*)d_in[2];
    const float* Wq         = (const float*)d_in[3];
    const float* bq         = (const float*)d_in[4];
    const float* Wk         = (const float*)d_in[5];
    const float* bk         = (const float*)d_in[6];
    const float* Wv         = (const float*)d_in[7];
    const float* bv         = (const float*)d_in[8];
    const float* Wo         = (const float*)d_in[9];
    const float* bo         = (const float*)d_in[10];
    const float* W1         = (const float*)d_in[11];
    const float* b1         = (const float*)d_in[12];
    const float* W2         = (const float*)d_in[13];
    const float* b2         = (const float*)d_in[14];
    const float* ln1_scale  = (const float*)d_in[15];
    const float* ln1_bias   = (const float*)d_in[16];
    const float* ln2_scale  = (const float*)d_in[17];
    const float* ln2_bias   = (const float*)d_in[18];
    const float* log_tau    = (const float*)d_in[19];
    const float* attn_scale = (const float*)d_in[20];

    char* p = (char*)d_ws;
    unsigned short* qkvWt  = (unsigned short*)p; p += (size_t)QKV_ * DIM_ * 2;   // [1536][512] bf16
    unsigned short* WoT    = (unsigned short*)p; p += (size_t)DIM_ * DIM_ * 2;   // [512][512]
    unsigned short* W1T    = (unsigned short*)p; p += (size_t)FFN_ * DIM_ * 2;   // [2048][512]
    unsigned short* W2T    = (unsigned short*)p; p += (size_t)DIM_ * FFN_ * 2;   // [512][2048]
    float*          qkv_b  = (float*)p;          p += (size_t)QKV_ * 4;
    unsigned short* xn     = (unsigned short*)p; p += (size_t)TOK_ * DIM_ * 2;   // bf16
    float*          qf     = (float*)p;          p += (size_t)TOK_ * DIM_ * 4;   // fp32 q
    unsigned short* kvb    = (unsigned short*)p; p += (size_t)TOK_ * KV_ * 2;    // bf16 k|v
    unsigned short* attn_o = (unsigned short*)p; p += (size_t)TOK_ * DIM_ * 2;   // bf16
    float*          x1     = (float*)p;          p += (size_t)TOK_ * DIM_ * 4;
    unsigned short* x2n    = (unsigned short*)p; p += (size_t)TOK_ * DIM_ * 2;
    unsigned short* hbuf   = (unsigned short*)p; p += (size_t)TOK_ * FFN_ * 2;
    float*          pos_sq = (float*)p;          p += (size_t)TOK_ * 4;
    float*          posT   = (float*)p;          p += (size_t)B_ * 16 * N_ * 4;
    float*          tk_d   = (float*)p;          p += (size_t)TOK_ * K_ * 4;
    int*            tk_i   = (int*)p;            p += (size_t)TOK_ * K_ * 4;

    // --- fused prep: transposes + bias + pos_sq/posT + LN1 ---
    fused_prep_kernel<<<4118, 256, 0, stream>>>(Wq, Wk, Wv, Wo, W1, W2, bq, bk, bv,
                                                qkvWt, WoT, W1T, W2T, qkv_b,
                                                positions, pos_sq, posT,
                                                x, ln1_scale, ln1_bias, xn);

    // --- QKV GEMM: 64x128 tiles -> 768 blocks, double-buffered ---
    gemm_bf16_kernel<3,64,128><<<dim3(QKV_/128, TOK_/64), 256, 0, stream>>>(
        xn, qkvWt, qkv_b, nullptr, qf, kvb, QKV_, DIM_);

    // --- distances + top-k (2 rows/wave, posT float4 — R11 measured best) ---
    dist_topk_kernel<<<TOK_/4, 256, 0, stream>>>(positions, posT, pos_sq,
                                                 c_p, tk_i, tk_d);

    // --- sparse attention -> bf16 ---
    attn_kernel<<<(B_*NH_*N_)/4, 256, 0, stream>>>(qf, kvb, tk_i, tk_d,
                                                   log_tau, attn_scale,
                                                   (unsigned int*)attn_o);

    // --- x1 = x + attn_o @ Wo + bo (fp32), 64x64 -> 512 blocks, dbuf ---
    gemm_bf16_kernel<1,64,64><<<dim3(DIM_/64, TOK_/64), 256, 0, stream>>>(
        attn_o, WoT, bo, x, x1, nullptr, DIM_, DIM_);

    // --- LN2 -> bf16 ---
    layernorm_kernel<<<TOK_/4, 256, 0, stream>>>(x1, ln2_scale, ln2_bias, x2n);

    // --- FFN1: gelu(x2n @ W1 + b1) -> bf16 h, 64x128 -> 1024 blocks, dbuf ---
    gemm_bf16_kernel<2,64,128><<<dim3(FFN_/128, TOK_/64), 256, 0, stream>>>(
        x2n, W1T, b1, nullptr, nullptr, hbuf, FFN_, DIM_);

    // --- FFN2: out = x1 + h @ W2 + b2 (fp32), 64x64 -> 512 blocks, dbuf ---
    gemm_bf16_kernel<1,64,64><<<dim3(DIM_/64, TOK_/64), 256, 0, stream>>>(
        hbuf, W2T, b2, x1, (float*)d_out, nullptr, DIM_, FFN_);
}